// Round 15
// baseline (86.331 us; speedup 1.0000x reference)
//
#include <hip/hip_runtime.h>
#include <hip/hip_bf16.h>
#include <cstdint>
#include <cstddef>

#define NB 64
#define NS 1024
#define NE 256
#define NH 256
#define NC 20
#define MAXS 16     // pblk slots per 16-token chunk; rel-sid provably <= 15

typedef short bf16x8 __attribute__((ext_vector_type(8)));
typedef float f32x4 __attribute__((ext_vector_type(4)));

// ---- workspace layout (bytes) ----
// pblk : 4096 chunks x 16 slots x 256 f32 = 67108864 @ 0
// dsum : 64 rows x 8 tiles x 256 f32     =   524288 @ 67108864
#define WS_PBLK 0
#define WS_DSUM 67108864

__device__ inline float bf2f(unsigned short u) {
    return __uint_as_float(((unsigned int)u) << 16);
}
__device__ inline unsigned short f2bf(float f) {
    unsigned int x = __float_as_uint(f);
    unsigned int r = (x + 0x7FFFu + ((x >> 16) & 1u)) >> 16;
    return (unsigned short)r;
}
__device__ inline float fast_tanh(float x) {
    float e = __expf(2.f * x);
    return 1.f - 2.f / (e + 1.f);
}

// ---- kernel 1: h = tanh(emb[x]@W1+b1) -> per-16-token-chunk segment partials ----
// 512 blocks x 512 thr (8 waves); wave owns 32 cols. W1 read directly (L2-hot).
// One barrier per 16-token tile; segment reduce in MFMA C-layout registers.
__global__ __launch_bounds__(512, 4) void gemm1_kernel(
    const int* __restrict__ batch_x, const float* __restrict__ emb,
    const float* __restrict__ W1, const float* __restrict__ b1,
    float* __restrict__ pblk)
{
    __shared__ unsigned short As[2][16][264];   // 16.9 KB dbuf
    __shared__ int sidtab[128];

    int tid = threadIdx.x;
    int lane = tid & 63;
    int w = tid >> 6;
    int lr = lane & 15;
    int g = lane >> 4;
    int kb0 = g * 8;
    int base = blockIdx.x * 128;

    // block-local sentence ids (wave 0): sid = #boundaries strictly before token
    if (w == 0) {
        int cnt = 0;
        #pragma unroll
        for (int c = 0; c < 2; ++c) {
            int t = c * 64 + lane;
            bool isb = (batch_x[base + t] == 1);
            unsigned long long bal = __ballot(isb);
            int pre = __popcll(bal & ((1ull << lane) - 1ull));
            sidtab[t] = cnt + pre;
            cnt += __popcll(bal);
        }
    }

    // B fragments direct from W1 (f32 -> bf16): lane lr covers col, per-k 64B coalesced
    bf16x8 Bf[16];
    #pragma unroll
    for (int ks = 0; ks < 8; ++ks) {
        #pragma unroll
        for (int n = 0; n < 2; ++n) {
            int col = w * 32 + n * 16 + lr;
            bf16x8 v;
            #pragma unroll
            for (int e = 0; e < 8; ++e) {
                int k = ks * 32 + kb0 + e;
                v[e] = (short)f2bf(W1[k * NH + col]);
            }
            Bf[ks * 2 + n] = v;
        }
    }
    float bb[2];
    #pragma unroll
    for (int n = 0; n < 2; ++n) bb[n] = b1[w * 32 + n * 16 + lr];

    // stage tile 0
    float4 gr[2];
    #pragma unroll
    for (int i = 0; i < 2; ++i) {
        int f = tid + i * 512;
        int row = f >> 6, c4 = (f & 63) * 4;
        int xv = batch_x[base + row];
        gr[i] = *reinterpret_cast<const float4*>(emb + (size_t)xv * NE + c4);
    }
    #pragma unroll
    for (int i = 0; i < 2; ++i) {
        int f = tid + i * 512;
        int row = f >> 6, c4 = (f & 63) * 4;
        ushort4 u;
        u.x = f2bf(gr[i].x); u.y = f2bf(gr[i].y); u.z = f2bf(gr[i].z); u.w = f2bf(gr[i].w);
        *reinterpret_cast<ushort4*>(&As[0][row][c4]) = u;
    }

    for (int t = 0; t < 8; ++t) {
        __syncthreads();                 // As[cur] ready; also fences prev reads of As[cur^1]
        int cur = t & 1;

        if (t + 1 < 8) {                 // issue next gather early
            #pragma unroll
            for (int i = 0; i < 2; ++i) {
                int f = tid + i * 512;
                int row = f >> 6, c4 = (f & 63) * 4;
                int xv = batch_x[base + (t + 1) * 16 + row];
                gr[i] = *reinterpret_cast<const float4*>(emb + (size_t)xv * NE + c4);
            }
        }

        f32x4 acc[2];
        #pragma unroll
        for (int n = 0; n < 2; ++n) acc[n] = (f32x4){0.f, 0.f, 0.f, 0.f};
        #pragma unroll
        for (int ks = 0; ks < 8; ++ks) {
            bf16x8 a = *reinterpret_cast<const bf16x8*>(&As[cur][lr][ks * 32 + kb0]);
            #pragma unroll
            for (int n = 0; n < 2; ++n)
                acc[n] = __builtin_amdgcn_mfma_f32_16x16x32_bf16(a, Bf[ks * 2 + n], acc[n], 0, 0, 0);
        }

        if (t + 1 < 8) {                 // stage next tile into other buffer
            #pragma unroll
            for (int i = 0; i < 2; ++i) {
                int f = tid + i * 512;
                int row = f >> 6, c4 = (f & 63) * 4;
                ushort4 u;
                u.x = f2bf(gr[i].x); u.y = f2bf(gr[i].y); u.z = f2bf(gr[i].z); u.w = f2bf(gr[i].w);
                *reinterpret_cast<ushort4*>(&As[cur ^ 1][row][c4]) = u;
            }
        }

        // tanh (f32, no bf16 round-trip)
        float h[2][4];
        #pragma unroll
        for (int n = 0; n < 2; ++n)
            #pragma unroll
            for (int j = 0; j < 4; ++j)
                h[n][j] = fast_tanh(acc[n][j] + bb[n]);

        // in-register segment reduce over this 16-token chunk (C-layout: rows g*4+j)
        int tb = t * 16;
        int sbase = sidtab[tb];
        int nseg = sidtab[tb + 15] - sbase + 1;       // <= 16 guaranteed
        int sid_[4];
        #pragma unroll
        for (int j = 0; j < 4; ++j) sid_[j] = sidtab[tb + g * 4 + j] - sbase;

        size_t chunkoff = (size_t)(blockIdx.x * 8 + t) * (MAXS * NH);
        for (int s = 0; s < nseg; ++s) {
            #pragma unroll
            for (int n = 0; n < 2; ++n) {
                float v = 0.f;
                #pragma unroll
                for (int j = 0; j < 4; ++j)
                    v += (sid_[j] == s) ? h[n][j] : 0.f;
                v += __shfl_xor(v, 16, 64);
                v += __shfl_xor(v, 32, 64);
                if (g == 0)
                    pblk[chunkoff + (size_t)s * NH + (w * 32 + n * 16 + lr)] = v;
            }
        }
    }
}

// ---- kernel 2: per-tile sent_hidden + partial doc sums; self-contained row scan ----
// grid (8, NB), 256 thr; W2 read directly (L2-hot)
__global__ __launch_bounds__(256, 2) void sgemm_kernel(
    const int* __restrict__ batch_x, const float* __restrict__ pblk,
    const float* __restrict__ W2, const float* __restrict__ b2,
    float* __restrict__ dsum)
{
    __shared__ int st[NS + 1];
    __shared__ int pref16[64];
    __shared__ int L_sh;
    __shared__ unsigned short ms[16][264];

    int b = blockIdx.y;
    int t = blockIdx.x;
    int i0 = t * 16;
    int tid = threadIdx.x;
    int lane = tid & 63;
    int w = tid >> 6;
    int lr = lane & 15;
    int g = lane >> 4;
    int kb0 = g * 8;

    // wave 0: boundary scan of row b (starts, 16-token-chunk prefixes, L)
    if (w == 0) {
        const int* row = batch_x + b * NS;
        int cnt = 0;
        if (lane == 0) st[0] = 0;
        for (int it = 0; it < 16; ++it) {
            bool isb = (row[it * 64 + lane] == 1);
            unsigned long long bal = __ballot(isb);
            if (lane < 4)
                pref16[it * 4 + lane] = cnt + __popcll(bal & ((1ull << (16 * lane)) - 1ull));
            int pre = __popcll(bal & ((1ull << lane) - 1ull));
            if (isb) st[cnt + pre + 1] = it * 64 + lane + 1;
            cnt += __popcll(bal);
        }
        if (lane == 0) L_sh = cnt;
    }

    // Bf direct from W2 (f32 -> bf16), overlapped with wave-0 scan
    bf16x8 Bf[32];
    #pragma unroll
    for (int ks = 0; ks < 8; ++ks) {
        #pragma unroll
        for (int n = 0; n < 4; ++n) {
            int col = w * 64 + n * 16 + lr;
            bf16x8 v;
            #pragma unroll
            for (int e = 0; e < 8; ++e) {
                int k = ks * 32 + kb0 + e;
                v[e] = (short)f2bf(W2[k * NH + col]);
            }
            Bf[ks * 4 + n] = v;
        }
    }
    float bb[4];
    #pragma unroll
    for (int n = 0; n < 4; ++n) bb[n] = b2[w * 64 + n * 16 + lr];

    __syncthreads();
    int L = L_sh;
    if (i0 >= L) return;   // uniform across block

    // reconstruct 16 sentence means from chunk partials; thread tid = column
    for (int s = 0; s < 16; ++s) {
        int i = i0 + s;
        float m = 0.f;
        if (i < L) {
            int s0 = st[i], e0 = st[i + 1];
            float sum = 0.f;
            int cb1 = (e0 - 1) >> 4;
            for (int cb = s0 >> 4; cb <= cb1; ++cb) {
                int rel = i - pref16[cb];           // provably in [0,15]
                sum += pblk[((size_t)(b * 64 + cb) * MAXS + rel) * NH + tid];
            }
            m = sum / (float)(e0 - s0);
        }
        ms[s][tid] = f2bf(m);
    }
    __syncthreads();

    f32x4 acc[4];
    #pragma unroll
    for (int n = 0; n < 4; ++n) acc[n] = (f32x4){0.f, 0.f, 0.f, 0.f};
    #pragma unroll
    for (int ks = 0; ks < 8; ++ks) {
        bf16x8 a = *reinterpret_cast<const bf16x8*>(&ms[lr][ks * 32 + kb0]);
        #pragma unroll
        for (int n = 0; n < 4; ++n)
            acc[n] = __builtin_amdgcn_mfma_f32_16x16x32_bf16(a, Bf[ks * 4 + n], acc[n], 0, 0, 0);
    }

    // tile-partial doc column sums (valid rows only), butterfly over g-groups
    float* dp = dsum + ((size_t)b * 8 + t) * NH;
    #pragma unroll
    for (int n = 0; n < 4; ++n) {
        float v = 0.f;
        #pragma unroll
        for (int j = 0; j < 4; ++j) {
            int srow = i0 + g * 4 + j;
            float hv = tanhf(acc[n][j] + bb[n]);
            v += (srow < L) ? hv : 0.f;
        }
        v += __shfl_xor(v, 16, 64);
        v += __shfl_xor(v, 32, 64);
        if (g == 0) dp[w * 64 + n * 16 + lr] = v;
    }
}

// ---- kernel 3: doc mean -> @W3 + b3 -> log_softmax (recounts L locally) ----
__global__ __launch_bounds__(256) void doc_kernel(
    const int* __restrict__ batch_x, const float* __restrict__ dsum,
    const float* __restrict__ W3, const float* __restrict__ b3,
    float* __restrict__ out)
{
    __shared__ int L_sh;
    __shared__ float d[NH];
    __shared__ float cat[NC];

    int b = blockIdx.x;
    int j = threadIdx.x;

    if (j < 64) {
        const int* row = batch_x + b * NS;
        int cnt = 0;
        for (int it = 0; it < 16; ++it)
            cnt += __popcll(__ballot(row[it * 64 + j] == 1));
        if (j == 0) L_sh = cnt;
    }
    __syncthreads();
    int L = L_sh;
    int ntiles = (L + 15) >> 4;

    float s = 0.f;
    for (int t = 0; t < ntiles; ++t)      // fixed ascending order: deterministic
        s += dsum[((size_t)b * 8 + t) * NH + j];
    d[j] = s / (float)L;
    __syncthreads();

    if (j < NC) {
        float a = b3[j];
        #pragma unroll 8
        for (int k = 0; k < NH; ++k) a += d[k] * W3[k * NC + j];
        cat[j] = a;
    }
    __syncthreads();

    if (j == 0) {
        float mx = -1e30f;
        for (int c = 0; c < NC; ++c) mx = fmaxf(mx, cat[c]);
        float se = 0.f;
        for (int c = 0; c < NC; ++c) se += expf(cat[c] - mx);
        float lse = logf(se) + mx;
        for (int c = 0; c < NC; ++c) out[b * NC + c] = cat[c] - lse;
    }
}

extern "C" void kernel_launch(void* const* d_in, const int* in_sizes, int n_in,
                              void* d_out, int out_size, void* d_ws, size_t ws_size,
                              hipStream_t stream) {
    const int*   batch_x = (const int*)d_in[0];
    const float* emb = (const float*)d_in[2];
    const float* W1  = (const float*)d_in[3];
    const float* b1  = (const float*)d_in[4];
    const float* W2  = (const float*)d_in[5];
    const float* b2  = (const float*)d_in[6];
    const float* W3  = (const float*)d_in[7];
    const float* b3  = (const float*)d_in[8];
    float* out = (float*)d_out;

    char* ws = (char*)d_ws;
    float* pblk = (float*)(ws + WS_PBLK);
    float* dsum = (float*)(ws + WS_DSUM);

    hipLaunchKernelGGL(gemm1_kernel, dim3((NB * NS) / 128), dim3(512), 0, stream,
                       batch_x, emb, W1, b1, pblk);
    hipLaunchKernelGGL(sgemm_kernel, dim3(8, NB), dim3(256), 0, stream,
                       batch_x, pblk, W2, b2, dsum);
    hipLaunchKernelGGL(doc_kernel, dim3(NB), dim3(256), 0, stream,
                       batch_x, dsum, W3, b3, out);
}

// Round 16
// 80.739 us; speedup vs baseline: 1.0693x; 1.0693x over previous
//
#include <hip/hip_runtime.h>
#include <hip/hip_bf16.h>
#include <cstdint>
#include <cstddef>

#define NB 64
#define NS 1024
#define NE 256
#define NH 256
#define NC 20
#define MAXS 16     // pblk slots per 16-token chunk; rel-sid provably <= 15

typedef short bf16x8 __attribute__((ext_vector_type(8)));
typedef float f32x4 __attribute__((ext_vector_type(4)));

// ---- workspace layout (bytes) ----
// W1T     131072 @ 0
// W2T     131072 @ 131072
// starts  262400 @ 262144
// lens       256 @ 524544
// pref16   16384 @ 524800   (boundaries before each 16-token chunk, 64/row)
// pblk  67108864 @ 541184   (4096 chunks x 16 slots x 256 f32)
// dsum    524288 @ 67650048 (64 rows x 8 tiles x 256 f32)
// total ~68.2 MB
#define WS_W1T    0
#define WS_W2T    131072
#define WS_STARTS 262144
#define WS_LENS   524544
#define WS_PREF16 524800
#define WS_PBLK   541184
#define WS_DSUM   67650048

__device__ inline float bf2f(unsigned short u) {
    return __uint_as_float(((unsigned int)u) << 16);
}
__device__ inline unsigned short f2bf(float f) {
    unsigned int x = __float_as_uint(f);
    unsigned int r = (x + 0x7FFFu + ((x >> 16) & 1u)) >> 16;
    return (unsigned short)r;
}
__device__ inline float fast_tanh(float x) {
    float e = __expf(2.f * x);
    return 1.f - 2.f / (e + 1.f);
}

// ---- kernel 0: W1->W1T, W2->W2T (bf16 transposed) + boundary scan ----
__global__ void setup_kernel(const float* __restrict__ W1, const float* __restrict__ W2,
                             const int* __restrict__ x,
                             unsigned short* __restrict__ W1T, unsigned short* __restrict__ W2T,
                             int* __restrict__ starts, int* __restrict__ lens,
                             int* __restrict__ pref16) {
    int blk = blockIdx.x;
    if (blk < 512) {
        int idx = blk * 256 + threadIdx.x;
        if (idx < NE * NH) {
            int h = idx >> 8, e = idx & 255;
            W1T[idx] = f2bf(W1[e * NH + h]);          // W1T[h][e]
        } else {
            int i = idx - NE * NH;
            int j = i >> 8, k = i & 255;
            W2T[i] = f2bf(W2[k * NH + j]);            // W2T[j][k]
        }
    } else {
        if (threadIdx.x >= 64) return;
        int b = blk - 512;
        int lane = threadIdx.x;
        const int* row = x + b * NS;
        int* st = starts + b * (NS + 1);
        if (lane == 0) st[0] = 0;
        int cnt = 0;
        for (int it = 0; it < 16; ++it) {
            int s = it * 64 + lane;
            bool isb = (row[s] == 1);
            unsigned long long bal = __ballot(isb);
            if (lane < 4)
                pref16[b * 64 + it * 4 + lane] =
                    cnt + __popcll(bal & ((1ull << (16 * lane)) - 1ull));
            int pre = __popcll(bal & ((1ull << lane) - 1ull));
            if (isb) st[cnt + pre + 1] = s + 1;
            cnt += __popcll(bal);
        }
        if (lane == 0) lens[b] = cnt;
    }
}

// ---- kernel 1: h = tanh(emb[x]@W1+b1) -> per-16-token-chunk segment partials ----
// 512 blocks x 512 thr (8 waves); wave owns 32 cols; Bf from prepacked W1T.
// ONE barrier per tile; segment reduce in MFMA C-layout registers (f32).
__global__ __launch_bounds__(512, 4) void gemm1_kernel(
    const int* __restrict__ batch_x, const float* __restrict__ emb,
    const unsigned short* __restrict__ W1T, const float* __restrict__ b1,
    float* __restrict__ pblk)
{
    __shared__ unsigned short As[2][16][264];   // 16.9 KB dbuf
    __shared__ int sidtab[128];

    int tid = threadIdx.x;
    int lane = tid & 63;
    int w = tid >> 6;
    int lr = lane & 15;
    int g = lane >> 4;
    int kb0 = g * 8;
    int base = blockIdx.x * 128;

    // block-local sentence ids (wave 0): sid = #boundaries strictly before token
    if (w == 0) {
        int cnt = 0;
        #pragma unroll
        for (int c = 0; c < 2; ++c) {
            int t = c * 64 + lane;
            bool isb = (batch_x[base + t] == 1);
            unsigned long long bal = __ballot(isb);
            int pre = __popcll(bal & ((1ull << lane) - 1ull));
            sidtab[t] = cnt + pre;
            cnt += __popcll(bal);
        }
    }

    // loop-invariant B fragments from W1T (16 x 16B loads) + bias
    bf16x8 Bf[16];
    #pragma unroll
    for (int ks = 0; ks < 8; ++ks)
        #pragma unroll
        for (int n = 0; n < 2; ++n)
            Bf[ks * 2 + n] = *reinterpret_cast<const bf16x8*>(
                W1T + (size_t)(w * 32 + n * 16 + lr) * NE + ks * 32 + kb0);
    float bb[2];
    #pragma unroll
    for (int n = 0; n < 2; ++n) bb[n] = b1[w * 32 + n * 16 + lr];

    // stage tile 0
    float4 gr[2];
    #pragma unroll
    for (int i = 0; i < 2; ++i) {
        int f = tid + i * 512;
        int row = f >> 6, c4 = (f & 63) * 4;
        int xv = batch_x[base + row];
        gr[i] = *reinterpret_cast<const float4*>(emb + (size_t)xv * NE + c4);
    }
    #pragma unroll
    for (int i = 0; i < 2; ++i) {
        int f = tid + i * 512;
        int row = f >> 6, c4 = (f & 63) * 4;
        ushort4 u;
        u.x = f2bf(gr[i].x); u.y = f2bf(gr[i].y); u.z = f2bf(gr[i].z); u.w = f2bf(gr[i].w);
        *reinterpret_cast<ushort4*>(&As[0][row][c4]) = u;
    }

    for (int t = 0; t < 8; ++t) {
        __syncthreads();                 // As[cur] staged (also fences As[cur^1] reuse)
        int cur = t & 1;

        if (t + 1 < 8) {                 // issue next gather early
            #pragma unroll
            for (int i = 0; i < 2; ++i) {
                int f = tid + i * 512;
                int row = f >> 6, c4 = (f & 63) * 4;
                int xv = batch_x[base + (t + 1) * 16 + row];
                gr[i] = *reinterpret_cast<const float4*>(emb + (size_t)xv * NE + c4);
            }
        }

        f32x4 acc[2];
        #pragma unroll
        for (int n = 0; n < 2; ++n) acc[n] = (f32x4){0.f, 0.f, 0.f, 0.f};
        #pragma unroll
        for (int ks = 0; ks < 8; ++ks) {
            bf16x8 a = *reinterpret_cast<const bf16x8*>(&As[cur][lr][ks * 32 + kb0]);
            #pragma unroll
            for (int n = 0; n < 2; ++n)
                acc[n] = __builtin_amdgcn_mfma_f32_16x16x32_bf16(a, Bf[ks * 2 + n], acc[n], 0, 0, 0);
        }

        if (t + 1 < 8) {                 // stage next tile into other buffer
            #pragma unroll
            for (int i = 0; i < 2; ++i) {
                int f = tid + i * 512;
                int row = f >> 6, c4 = (f & 63) * 4;
                ushort4 u;
                u.x = f2bf(gr[i].x); u.y = f2bf(gr[i].y); u.z = f2bf(gr[i].z); u.w = f2bf(gr[i].w);
                *reinterpret_cast<ushort4*>(&As[cur ^ 1][row][c4]) = u;
            }
        }

        // tanh (f32 partials, no bf16 round-trip)
        float h[2][4];
        #pragma unroll
        for (int n = 0; n < 2; ++n)
            #pragma unroll
            for (int j = 0; j < 4; ++j)
                h[n][j] = fast_tanh(acc[n][j] + bb[n]);

        // in-register segment reduce over this 16-token chunk (C rows = g*4+j)
        int tb = t * 16;
        int sbase = sidtab[tb];
        int nseg = sidtab[tb + 15] - sbase + 1;       // <= 16 guaranteed
        int sid_[4];
        #pragma unroll
        for (int j = 0; j < 4; ++j) sid_[j] = sidtab[tb + g * 4 + j] - sbase;

        size_t chunkoff = (size_t)(blockIdx.x * 8 + t) * (MAXS * NH);
        for (int s = 0; s < nseg; ++s) {
            #pragma unroll
            for (int n = 0; n < 2; ++n) {
                float v = 0.f;
                #pragma unroll
                for (int j = 0; j < 4; ++j)
                    v += (sid_[j] == s) ? h[n][j] : 0.f;
                v += __shfl_xor(v, 16, 64);
                v += __shfl_xor(v, 32, 64);
                if (g == 0)
                    pblk[chunkoff + (size_t)s * NH + (w * 32 + n * 16 + lr)] = v;
            }
        }
    }
}

// ---- kernel 2: per-tile sent_hidden + partial doc sums (W2T + ws metadata) ----
// grid (8, NB), 256 thr
__global__ __launch_bounds__(256, 2) void sgemm_kernel(
    const float* __restrict__ pblk, const int* __restrict__ starts,
    const int* __restrict__ lens, const int* __restrict__ pref16,
    const unsigned short* __restrict__ W2T, const float* __restrict__ b2,
    float* __restrict__ dsum)
{
    int b = blockIdx.y;
    int t = blockIdx.x;
    int i0 = t * 16;
    int L = lens[b];
    if (i0 >= L) return;

    int tid = threadIdx.x;
    int lane = tid & 63;
    int w = tid >> 6;
    int lr = lane & 15;
    int g = lane >> 4;
    int kb0 = g * 8;

    __shared__ unsigned short ms[16][264];
    bf16x8 Bf[32];
    #pragma unroll
    for (int ks = 0; ks < 8; ++ks)
        #pragma unroll
        for (int n = 0; n < 4; ++n)
            Bf[ks * 4 + n] = *reinterpret_cast<const bf16x8*>(
                W2T + (size_t)(w * 64 + n * 16 + lr) * NH + ks * 32 + kb0);
    float bb[4];
    #pragma unroll
    for (int n = 0; n < 4; ++n) bb[n] = b2[w * 64 + n * 16 + lr];

    // reconstruct 16 sentence means from 16-token-chunk partials; thread tid = col
    const int* st = starts + b * (NS + 1);
    const int* pf = pref16 + b * 64;
    for (int s = 0; s < 16; ++s) {
        int i = i0 + s;
        float m = 0.f;
        if (i < L) {
            int s0 = st[i], e0 = st[i + 1];
            float sum = 0.f;
            int cb1 = (e0 - 1) >> 4;
            for (int cb = s0 >> 4; cb <= cb1; ++cb) {
                int rel = i - pf[cb];               // in [0,15]
                sum += pblk[((size_t)(b * 64 + cb) * MAXS + rel) * NH + tid];
            }
            m = sum / (float)(e0 - s0);
        }
        ms[s][tid] = f2bf(m);
    }
    __syncthreads();

    f32x4 acc[4];
    #pragma unroll
    for (int n = 0; n < 4; ++n) acc[n] = (f32x4){0.f, 0.f, 0.f, 0.f};
    #pragma unroll
    for (int ks = 0; ks < 8; ++ks) {
        bf16x8 a = *reinterpret_cast<const bf16x8*>(&ms[lr][ks * 32 + kb0]);
        #pragma unroll
        for (int n = 0; n < 4; ++n)
            acc[n] = __builtin_amdgcn_mfma_f32_16x16x32_bf16(a, Bf[ks * 4 + n], acc[n], 0, 0, 0);
    }

    // tile-partial doc column sums (valid rows only), butterfly over g-groups
    float* dp = dsum + ((size_t)b * 8 + t) * NH;
    #pragma unroll
    for (int n = 0; n < 4; ++n) {
        float v = 0.f;
        #pragma unroll
        for (int j = 0; j < 4; ++j) {
            int srow = i0 + g * 4 + j;
            float hv = tanhf(acc[n][j] + bb[n]);
            v += (srow < L) ? hv : 0.f;
        }
        v += __shfl_xor(v, 16, 64);
        v += __shfl_xor(v, 32, 64);
        if (g == 0) dp[w * 64 + n * 16 + lr] = v;
    }
}

// ---- kernel 3: doc mean -> @W3 + b3 -> log_softmax ----
__global__ __launch_bounds__(256) void doc_kernel(
    const float* __restrict__ dsum, const int* __restrict__ lens,
    const float* __restrict__ W3, const float* __restrict__ b3,
    float* __restrict__ out)
{
    int b = blockIdx.x;
    int j = threadIdx.x;
    int L = lens[b];
    int ntiles = (L + 15) >> 4;

    float s = 0.f;
    for (int t = 0; t < ntiles; ++t)      // fixed ascending order: deterministic
        s += dsum[((size_t)b * 8 + t) * NH + j];

    __shared__ float d[NH];
    d[j] = s / (float)L;
    __syncthreads();

    __shared__ float cat[NC];
    if (j < NC) {
        float a = b3[j];
        #pragma unroll 8
        for (int k = 0; k < NH; ++k) a += d[k] * W3[k * NC + j];
        cat[j] = a;
    }
    __syncthreads();

    if (j == 0) {
        float mx = -1e30f;
        for (int c = 0; c < NC; ++c) mx = fmaxf(mx, cat[c]);
        float se = 0.f;
        for (int c = 0; c < NC; ++c) se += expf(cat[c] - mx);
        float lse = logf(se) + mx;
        for (int c = 0; c < NC; ++c) out[b * NC + c] = cat[c] - lse;
    }
}

extern "C" void kernel_launch(void* const* d_in, const int* in_sizes, int n_in,
                              void* d_out, int out_size, void* d_ws, size_t ws_size,
                              hipStream_t stream) {
    const int*   batch_x = (const int*)d_in[0];
    const float* emb = (const float*)d_in[2];
    const float* W1  = (const float*)d_in[3];
    const float* b1  = (const float*)d_in[4];
    const float* W2  = (const float*)d_in[5];
    const float* b2  = (const float*)d_in[6];
    const float* W3  = (const float*)d_in[7];
    const float* b3  = (const float*)d_in[8];
    float* out = (float*)d_out;

    char* ws = (char*)d_ws;
    unsigned short* W1T   = (unsigned short*)(ws + WS_W1T);
    unsigned short* W2T   = (unsigned short*)(ws + WS_W2T);
    int*            starts= (int*)(ws + WS_STARTS);
    int*            lens  = (int*)(ws + WS_LENS);
    int*            pref16= (int*)(ws + WS_PREF16);
    float*          pblk  = (float*)(ws + WS_PBLK);
    float*          dsum  = (float*)(ws + WS_DSUM);

    hipLaunchKernelGGL(setup_kernel, dim3(512 + NB), dim3(256), 0, stream,
                       W1, W2, batch_x, W1T, W2T, starts, lens, pref16);
    hipLaunchKernelGGL(gemm1_kernel, dim3((NB * NS) / 128), dim3(512), 0, stream,
                       batch_x, emb, W1T, b1, pblk);
    hipLaunchKernelGGL(sgemm_kernel, dim3(8, NB), dim3(256), 0, stream,
                       pblk, starts, lens, pref16, W2T, b2, dsum);
    hipLaunchKernelGGL(doc_kernel, dim3(NB), dim3(256), 0, stream,
                       dsum, lens, W3, b3, out);
}